// Round 10
// baseline (340.434 us; speedup 1.0000x reference)
//
#include <hip/hip_runtime.h>

// ---------------------------------------------------------------------------
// MambaBlock fused pipeline, MI355X (gfx950) — round 16
// B=2, L=1024, D_MODEL=1024, D_INNER=2048, D_STATE=16, D_CONV=4, DT_RANK=64
//
// Round-15 post-mortem: NCHUNK=64 with 8ch/block DOUBLED xdbl fetch (166 MB,
// 512 blocks x fixed per-block row traffic) -> scan 59.7us, VALUBusy 20%.
// Lesson: block count multiplies xdbl traffic; parallelism must come from
// within the block.
// Round-16 scan: 256 blocks (16 ch/block, zero traffic growth), 1024-thread
// blocks (NCHUNK=64, CL=16) -> 16 waves/CU from ONE block; dlt/uu cached in
// registers across phases (CL=16 makes it fit; fully-unrolled -> no scratch)
// so phase 3 skips delta (16 MB) + ucbf (8 MB) re-reads. sH stride 1032.
// __launch_bounds__(1024,4) caps VGPR at 128.
// ---------------------------------------------------------------------------

typedef unsigned short u16;
typedef unsigned int   u32;

#define B_SZ 2
#define L_SZ 1024
#define DM   1024
#define DI   2048
#define DS   16
#define DTR  64
#define NXD  96      /* DTR + 2*DS */
#define NCHUNK 64
#define CL   16      /* chunk length: NCHUNK*CL = L */
#define KSPLIT 8     /* split-K for skinny x_dbl GEMM */
#define KC     256   /* 2048 / KSPLIT */
#define SHS  1032    /* sH n-stride: 1024 + 8 (bank skew) */

typedef __bf16 bf16x8 __attribute__((ext_vector_type(8)));
typedef float  f32x4  __attribute__((ext_vector_type(4)));
typedef u16    u16x8  __attribute__((ext_vector_type(8)));

__device__ __forceinline__ u16 f2bf(float f) {
    u32 x = __float_as_uint(f);
    x += 0x7fffu + ((x >> 16) & 1u);   // round-to-nearest-even
    return (u16)(x >> 16);
}
__device__ __forceinline__ float bf2f(u16 v) {
    return __uint_as_float(((u32)v) << 16);
}

__device__ __forceinline__ void gld_lds16(const u16* g, u16* l) {
    __builtin_amdgcn_global_load_lds(
        (const __attribute__((address_space(1))) u32*)g,
        (__attribute__((address_space(3))) u32*)l, 16, 0, 0);
}

// raw workgroup barrier WITHOUT the compiler's vmcnt(0) drain
__device__ __forceinline__ void wg_barrier() {
    __asm__ volatile("" ::: "memory");
    __builtin_amdgcn_s_barrier();
    __asm__ volatile("" ::: "memory");
}
// s_waitcnt imm: vmcnt[3:0]+[15:14], expcnt[6:4], lgkmcnt[11:8]
#define WAIT_VM12() __builtin_amdgcn_s_waitcnt(0xF7C)
#define WAIT_VM9()  __builtin_amdgcn_s_waitcnt(0xF79)
#define WAIT_VM8()  __builtin_amdgcn_s_waitcnt(0xF78)
#define WAIT_VM6()  __builtin_amdgcn_s_waitcnt(0xF76)
#define WAIT_VM4()  __builtin_amdgcn_s_waitcnt(0xF74)
#define WAIT_VM3()  __builtin_amdgcn_s_waitcnt(0xF73)
#define WAIT_VM0()  __builtin_amdgcn_s_waitcnt(0xF70)
#define WAIT_LGKM0() __builtin_amdgcn_s_waitcnt(0xC07F)  /* vm off, exp off, lgkm 0 */

// ---------------------------------------------------------------------------
// Pipelined 128x128 GEMM (proven): C = A[M,K]*BT[N,K]^T, BK=32,
// 4-buffer LDS ring, prefetch distance 3 (4 loads/iter -> waits 12/8/4/0).
// op==2: Cb bf16 out.
// ---------------------------------------------------------------------------
__global__ __launch_bounds__(256) void gemm128p(
    const u16* __restrict__ A, const u16* __restrict__ BT,
    float* __restrict__ Cf, u16* __restrict__ Cb,
    int M, int N, int K, int op)
{
    __shared__ u16 As[4][128 * 32];
    __shared__ u16 Bs[4][128 * 32];

    const int tid  = threadIdx.x;
    const int wave = tid >> 6;
    const int lane = tid & 63;
    const int q    = lane >> 4;
    const int r16  = lane & 15;
    const int wm   = (wave & 1) * 64;
    const int wn   = (wave >> 1) * 64;
    const int m0   = blockIdx.y * 128;
    const int n0   = blockIdx.x * 128;

    const u16* gA0 = A  + (size_t)(m0 + (tid >> 2))      * K + (tid & 3) * 8;
    const u16* gA1 = A  + (size_t)(m0 + 64 + (tid >> 2)) * K + (tid & 3) * 8;
    const u16* gB0 = BT + (size_t)(n0 + (tid >> 2))      * K + (tid & 3) * 8;
    const u16* gB1 = BT + (size_t)(n0 + 64 + (tid >> 2)) * K + (tid & 3) * 8;

    const int niter = K >> 5;
    const int pre = niter < 3 ? niter : 3;
    for (int p = 0; p < pre; ++p) {
        const int k0 = p * 32;
        gld_lds16(gA0 + k0, &As[p][tid * 8]);
        gld_lds16(gA1 + k0, &As[p][2048 + tid * 8]);
        gld_lds16(gB0 + k0, &Bs[p][tid * 8]);
        gld_lds16(gB1 + k0, &Bs[p][2048 + tid * 8]);
    }

    f32x4 acc[4][4];
#pragma unroll
    for (int s = 0; s < 4; ++s)
#pragma unroll
        for (int j = 0; j < 4; ++j) acc[s][j] = (f32x4){0.f, 0.f, 0.f, 0.f};

    for (int it = 0; it < niter; ++it) {
        if (it + 3 < niter) {
            const int k0 = (it + 3) * 32;
            const int bi = (it + 3) & 3;
            gld_lds16(gA0 + k0, &As[bi][tid * 8]);
            gld_lds16(gA1 + k0, &As[bi][2048 + tid * 8]);
            gld_lds16(gB0 + k0, &Bs[bi][tid * 8]);
            gld_lds16(gB1 + k0, &Bs[bi][2048 + tid * 8]);
            WAIT_VM12();
        } else if (it + 2 < niter) {
            WAIT_VM8();
        } else if (it + 1 < niter) {
            WAIT_VM4();
        } else {
            WAIT_VM0();
        }
        wg_barrier();

        const int cur = it & 3;
        bf16x8 af[4], bfr[4];
#pragma unroll
        for (int s = 0; s < 4; ++s)
            af[s] = *(const bf16x8*)(&As[cur][(wm + s * 16 + r16) * 32 + q * 8]);
#pragma unroll
        for (int j = 0; j < 4; ++j)
            bfr[j] = *(const bf16x8*)(&Bs[cur][(wn + j * 16 + r16) * 32 + q * 8]);
#pragma unroll
        for (int s = 0; s < 4; ++s)
#pragma unroll
            for (int j = 0; j < 4; ++j)
                acc[s][j] = __builtin_amdgcn_mfma_f32_16x16x32_bf16(
                    af[s], bfr[j], acc[s][j], 0, 0, 0);

        wg_barrier();
    }

#pragma unroll
    for (int s = 0; s < 4; ++s) {
        const int row0 = m0 + wm + s * 16 + q * 4;
#pragma unroll
        for (int j = 0; j < 4; ++j) {
            const int col = n0 + wn + j * 16 + r16;
            if (op == 2) {
#pragma unroll
                for (int i = 0; i < 4; ++i)
                    Cb[(size_t)(row0 + i) * N + col] = f2bf(acc[s][j][i]);
            } else {
#pragma unroll
                for (int i = 0; i < 4; ++i)
                    Cf[(size_t)(row0 + i) * N + col] = acc[s][j][i];
            }
        }
    }
}

// ---------------------------------------------------------------------------
// GEMM-out: C[M,N] = A[M,K]*BT[N,K]^T, 128x64 tile, no split-K, direct fp32.
// Plain block mapping.
// ---------------------------------------------------------------------------
__global__ __launch_bounds__(256) void gemm_out64(
    const u16* __restrict__ A, const u16* __restrict__ BT,
    float* __restrict__ C, int M, int N, int K)
{
    __shared__ u16 As[4][128 * 32];   // 8 KB each
    __shared__ u16 Bs[4][64 * 32];    // 4 KB each

    const int tid  = threadIdx.x;
    const int wave = tid >> 6;
    const int lane = tid & 63;
    const int q    = lane >> 4;
    const int r16  = lane & 15;
    const int wm   = (wave & 1) * 64;
    const int wn   = (wave >> 1) * 32;
    const int m0   = blockIdx.y * 128;
    const int n0   = blockIdx.x * 64;

    const u16* gA0 = A  + (size_t)(m0 + (tid >> 2))      * K + (tid & 3) * 8;
    const u16* gA1 = A  + (size_t)(m0 + 64 + (tid >> 2)) * K + (tid & 3) * 8;
    const u16* gB0 = BT + (size_t)(n0 + (tid >> 2))      * K + (tid & 3) * 8;

    const int niter = K >> 5;
    const int pre = niter < 3 ? niter : 3;
    for (int p = 0; p < pre; ++p) {
        const int k0 = p * 32;
        gld_lds16(gA0 + k0, &As[p][tid * 8]);
        gld_lds16(gA1 + k0, &As[p][2048 + tid * 8]);
        gld_lds16(gB0 + k0, &Bs[p][tid * 8]);
    }

    f32x4 acc[4][2];
#pragma unroll
    for (int s = 0; s < 4; ++s)
#pragma unroll
        for (int j = 0; j < 2; ++j) acc[s][j] = (f32x4){0.f, 0.f, 0.f, 0.f};

    for (int it = 0; it < niter; ++it) {
        if (it + 3 < niter) {
            const int k0 = (it + 3) * 32;
            const int bi = (it + 3) & 3;
            gld_lds16(gA0 + k0, &As[bi][tid * 8]);
            gld_lds16(gA1 + k0, &As[bi][2048 + tid * 8]);
            gld_lds16(gB0 + k0, &Bs[bi][tid * 8]);
            WAIT_VM9();
        } else if (it + 2 < niter) {
            WAIT_VM6();
        } else if (it + 1 < niter) {
            WAIT_VM3();
        } else {
            WAIT_VM0();
        }
        wg_barrier();

        const int cur = it & 3;
        bf16x8 af[4], bfr[2];
#pragma unroll
        for (int s = 0; s < 4; ++s)
            af[s] = *(const bf16x8*)(&As[cur][(wm + s * 16 + r16) * 32 + q * 8]);
#pragma unroll
        for (int j = 0; j < 2; ++j)
            bfr[j] = *(const bf16x8*)(&Bs[cur][(wn + j * 16 + r16) * 32 + q * 8]);
#pragma unroll
        for (int s = 0; s < 4; ++s)
#pragma unroll
            for (int j = 0; j < 2; ++j)
                acc[s][j] = __builtin_amdgcn_mfma_f32_16x16x32_bf16(
                    af[s], bfr[j], acc[s][j], 0, 0, 0);

        wg_barrier();
    }

#pragma unroll
    for (int s = 0; s < 4; ++s) {
        const int row0 = m0 + wm + s * 16 + q * 4;
#pragma unroll
        for (int j = 0; j < 2; ++j) {
            const int col = n0 + wn + j * 16 + r16;
#pragma unroll
            for (int i = 0; i < 4; ++i)
                C[(size_t)(row0 + i) * N + col] = acc[s][j][i];
        }
    }
}

// ---------------------------------------------------------------------------
// Skinny-N split-K GEMM with FUSED conv+silu (x_dbl, N=96):
//  A-operand u[row,d] = silu(conv4(xz_u)[row,d] + cb[d]) computed on the fly:
//  stage xz tile (128 rows + 3-row halo) -> LDS -> conv in registers -> As.
//  Halo is ZERO when the tile starts a sequence ((m0 & (L_SZ-1)) == 0).
//  n0==0 blocks also store the computed u to ucbf (for the scan kernel).
//  Epilogue: atomicAdd into xdbl fp32 (zeroed by prep).
// ---------------------------------------------------------------------------
__global__ __launch_bounds__(256) void gemm_skinny_conv(
    const u16* __restrict__ xz, const u16* __restrict__ BT,
    const float* __restrict__ cw, const float* __restrict__ cb,
    u16* __restrict__ ucbf, float* xdbl)
{
    constexpr int LDT = 40;
    constexpr int XLD = 40;
    __shared__ u16 As[128 * LDT];      // 10.0 KB
    __shared__ u16 Bs[64 * LDT];       //  5.0 KB
    __shared__ u16 sxz[131 * XLD];     // 10.2 KB (rows: global m0-3 .. m0+127)
    __shared__ float cwS[1024];        //  4.0 KB (cw for d in [kcs, kcs+256))
    __shared__ float cbS[256];         //  1.0 KB

    const int tid  = threadIdx.x;
    const int wave = tid >> 6;
    const int lane = tid & 63;
    const int q    = lane >> 4;
    const int r16  = lane & 15;
    const int m0   = blockIdx.y * 128;
    const int n0   = blockIdx.x * 64;
    const int kcs  = blockIdx.z * KC;
    const int sr   = tid >> 2;          // 0..63
    const int ss   = (tid & 3) * 8;     // 0,8,16,24
    constexpr int XROW = 2 * DI;        // xz row stride (u16)
    const bool halo_ok = (m0 & (L_SZ - 1)) != 0;

    // conv weights/bias for this block's d-range -> LDS (once)
    *(f32x4*)(cwS + tid * 4) = *(const f32x4*)(cw + (size_t)kcs * 4 + tid * 4);
    if (tid < 64)
        *(f32x4*)(cbS + tid * 4) = *(const f32x4*)(cb + kcs + tid * 4);

    f32x4 acc[2][4];
#pragma unroll
    for (int s = 0; s < 2; ++s)
#pragma unroll
        for (int j = 0; j < 4; ++j) acc[s][j] = (f32x4){0.f, 0.f, 0.f, 0.f};

    const int bcol  = n0 + sr;
    const int bcolc = bcol < NXD ? bcol : NXD - 1;   // clamp; garbage cols dropped

    constexpr int NIT = KC / 32;
    // preload step-0 registers
    uint4 xa0 = *(const uint4*)(xz + (size_t)(m0 + sr)      * XROW + kcs + ss);
    uint4 xa1 = *(const uint4*)(xz + (size_t)(m0 + 64 + sr) * XROW + kcs + ss);
    uint4 bv  = *(const uint4*)(BT + (size_t)bcolc * DI + kcs + ss);
    uint4 hv  = (uint4){0, 0, 0, 0};
    const int hr  = tid >> 2;           // halo row 0..2 for tid<12
    const int hss = (tid & 3) * 8;
    if (tid < 12 && halo_ok)
        hv = *(const uint4*)(xz + (size_t)(m0 - 3 + hr) * XROW + kcs + hss);

    for (int it = 0; it < NIT; ++it) {
        const int k0 = kcs + it * 32;
        wg_barrier();                       // prev step done reading LDS
        *(uint4*)(sxz + (3 + sr) * XLD + ss)  = xa0;
        *(uint4*)(sxz + (67 + sr) * XLD + ss) = xa1;
        if (tid < 12) *(uint4*)(sxz + hr * XLD + hss) = hv;
        WAIT_LGKM0();
        wg_barrier();

        // prefetch next step's globals
        if (it + 1 < NIT) {
            const int kn = k0 + 32;
            xa0 = *(const uint4*)(xz + (size_t)(m0 + sr)      * XROW + kn + ss);
            xa1 = *(const uint4*)(xz + (size_t)(m0 + 64 + sr) * XROW + kn + ss);
            if (tid < 12 && halo_ok)
                hv = *(const uint4*)(xz + (size_t)(m0 - 3 + hr) * XROW + kn + hss);
        }

        // conv + silu for rows sr and 64+sr, d = k0+ss .. k0+ss+7
        f32x4 cwv[8];
#pragma unroll
        for (int i = 0; i < 8; ++i)
            cwv[i] = *(const f32x4*)(cwS + (it * 32 + ss + i) * 4);
        float s0[8], s1[8];
#pragma unroll
        for (int i = 0; i < 8; ++i) { s0[i] = cbS[it * 32 + ss + i]; s1[i] = s0[i]; }
#pragma unroll
        for (int j = 0; j < 4; ++j) {
            u16x8 t0 = *(const u16x8*)(sxz + (sr + j) * XLD + ss);
            u16x8 t1 = *(const u16x8*)(sxz + (64 + sr + j) * XLD + ss);
#pragma unroll
            for (int i = 0; i < 8; ++i) {
                s0[i] = fmaf(bf2f(t0[i]), cwv[i][j], s0[i]);
                s1[i] = fmaf(bf2f(t1[i]), cwv[i][j], s1[i]);
            }
        }
        u32 p0[4], p1[4];
#pragma unroll
        for (int i = 0; i < 4; ++i) {
            float v0a = s0[2*i],   v0b = s0[2*i+1];
            float v1a = s1[2*i],   v1b = s1[2*i+1];
            v0a = v0a / (1.f + __expf(-v0a));  v0b = v0b / (1.f + __expf(-v0b));
            v1a = v1a / (1.f + __expf(-v1a));  v1b = v1b / (1.f + __expf(-v1b));
            p0[i] = (u32)f2bf(v0a) | ((u32)f2bf(v0b) << 16);
            p1[i] = (u32)f2bf(v1a) | ((u32)f2bf(v1b) << 16);
        }
        uint4 ua = (uint4){p0[0], p0[1], p0[2], p0[3]};
        uint4 ub = (uint4){p1[0], p1[1], p1[2], p1[3]};
        *(uint4*)(As + sr * LDT + ss)        = ua;
        *(uint4*)(As + (64 + sr) * LDT + ss) = ub;
        *(uint4*)(Bs + sr * LDT + ss)        = bv;
        if (n0 == 0) {   // store u for the scan kernel (each (row,d) once)
            *(uint4*)(ucbf + (size_t)(m0 + sr)      * DI + k0 + ss) = ua;
            *(uint4*)(ucbf + (size_t)(m0 + 64 + sr) * DI + k0 + ss) = ub;
        }
        if (it + 1 < NIT)
            bv = *(const uint4*)(BT + (size_t)bcolc * DI + k0 + 32 + ss);
        WAIT_LGKM0();
        wg_barrier();

        bf16x8 af[2], bfr[4];
#pragma unroll
        for (int s = 0; s < 2; ++s)
            af[s] = *(const bf16x8*)(As + (wave * 32 + s * 16 + r16) * LDT + q * 8);
#pragma unroll
        for (int j = 0; j < 4; ++j)
            bfr[j] = *(const bf16x8*)(Bs + (j * 16 + r16) * LDT + q * 8);
#pragma unroll
        for (int s = 0; s < 2; ++s)
#pragma unroll
            for (int j = 0; j < 4; ++j)
                acc[s][j] = __builtin_amdgcn_mfma_f32_16x16x32_bf16(
                    af[s], bfr[j], acc[s][j], 0, 0, 0);
    }

#pragma unroll
    for (int s = 0; s < 2; ++s) {
        const int row0 = m0 + wave * 32 + s * 16 + q * 4;
#pragma unroll
        for (int j = 0; j < 4; ++j) {
            const int col = n0 + j * 16 + r16;
            if (col < NXD) {
#pragma unroll
                for (int i = 0; i < 4; ++i)
                    atomicAdd(&xdbl[(size_t)(row0 + i) * NXD + col], acc[s][j][i]);
            }
        }
    }
}

// ---------------------------------------------------------------------------
// delta GEMM, pure VALU (K=64 is too small for MFMA machinery):
// dlt[M=2048, N=2048] = softplus(xdbl[:, :64] @ W_dt + b_dt), W_dt fp32 direct.
// ---------------------------------------------------------------------------
__global__ __launch_bounds__(256) void delta_valu(
    const float* __restrict__ xdbl, const float* __restrict__ W_dt,
    const float* __restrict__ bias, float* __restrict__ dlt)
{
    __shared__ float sX[16][64];   // 4 KB

    const int tid = threadIdx.x;
    const int col = blockIdx.x * 256 + tid;
    const int r0  = blockIdx.y * 16;

    {   // stage xdbl[r0..r0+16)[0..64) -> LDS (vector, coalesced)
        const int r  = tid >> 4;          // 0..15
        const int c4 = (tid & 15) * 4;    // 0..60
        f32x4 v = *(const f32x4*)(xdbl + (size_t)(r0 + r) * NXD + c4);
        *(f32x4*)(&sX[r][c4]) = v;
    }
    __syncthreads();

    float acc[16];
#pragma unroll
    for (int r = 0; r < 16; ++r) acc[r] = 0.f;

    const float bv = bias[col];
#pragma unroll 4
    for (int k = 0; k < DTR; ++k) {
        float w = W_dt[(size_t)k * DI + col];
#pragma unroll
        for (int r = 0; r < 16; ++r)
            acc[r] = fmaf(sX[r][k], w, acc[r]);
    }

#pragma unroll
    for (int r = 0; r < 16; ++r) {
        float v = acc[r] + bv;
        v = (v > 20.f) ? v : log1pf(__expf(v));
        dlt[(size_t)(r0 + r) * DI + col] = v;
    }
}

// ---------------------------------------------------------------------------
// fused prep: x cast + 3 weight transposes + zero xdbl (for atomics)
// ---------------------------------------------------------------------------
__device__ __forceinline__ void tr_tile(
    const float* __restrict__ in, u16* __restrict__ out,
    int R, int C, int tr, int tc, int tid, float (*t)[33])
{
    const int tx = tid & 31, ty = tid >> 5;
    const int r0 = tr * 32, c0 = tc * 32;
#pragma unroll
    for (int i = 0; i < 4; ++i) {
        int r = r0 + ty + i * 8, c = c0 + tx;
        if (r < R && c < C) t[ty + i * 8][tx] = in[(size_t)r * C + c];
    }
    __syncthreads();
#pragma unroll
    for (int i = 0; i < 4; ++i) {
        int oR = c0 + ty + i * 8, oC = r0 + tx;
        if (oR < C && oC < R) out[(size_t)oR * R + oC] = f2bf(t[tx][ty + i * 8]);
    }
}

__global__ __launch_bounds__(256) void prep_kernel(
    const float* __restrict__ x,     u16* __restrict__ xbf,
    const float* __restrict__ W_in,  u16* __restrict__ winT,
    const float* __restrict__ W_out, u16* __restrict__ woutT,
    const float* __restrict__ W_x,   u16* __restrict__ wxT,
    float* __restrict__ xdbl)
{
    __shared__ float t[32][33];
    const int id  = blockIdx.x;
    const int tid = threadIdx.x;
    if (id < 4096) {                                   // W_in: 1024x4096
        tr_tile(W_in, winT, 1024, 4096, id >> 7, id & 127, tid, t);
    } else if (id < 6144) {                            // W_out: 2048x1024
        int i2 = id - 4096;
        tr_tile(W_out, woutT, 2048, 1024, i2 >> 5, i2 & 31, tid, t);
    } else if (id < 6336) {                            // W_x: 2048x96
        int i3 = id - 6144;
        tr_tile(W_x, wxT, 2048, 96, i3 / 3, i3 % 3, tid, t);
    } else if (id < 14528) {                           // x cast: 2,097,152
        int i = (id - 6336) * 256 + tid;
        xbf[i] = f2bf(x[i]);
    } else {                                           // zero xdbl: 196,608 f
        f32x4 z = (f32x4){0.f, 0.f, 0.f, 0.f};
        ((f32x4*)xdbl)[(size_t)(id - 14528) * 256 + tid] = z;
    }
}

// ---------------------------------------------------------------------------
// FUSED selective scan: pass1 + chunk-prefix + pass3 in ONE kernel.
// NCHUNK=64, CL=16. Block = 1024 thr = (chunk c = tid>>4) x (channel dd =
// tid&15). Grid = (DI/16, B) = 256 blocks (1/CU) -> 16 waves/CU from ONE
// block, xdbl traffic unchanged vs round 13 (256 blocks).
// dlt/uu cached in registers across phases (CL=16, fully unrolled) ->
// phase 3 skips delta + ucbf re-reads (-24 MB).
// LDS: sH [16][SHS=1032] (66 KB, 8-float skew) + sSum 4 KB.
// P identity: Pl = exp(Av[n]*sum(dlt)) — 1 exp/step in phase 2.
// e_n per row uses the arange power-tree (1 exp) w/ generic fallback.
// ---------------------------------------------------------------------------
#define EXP_TREE(e, p1)                                               \
    {                                                                 \
        float p2 = (p1) * (p1), p4 = p2 * p2, p8 = p4 * p4;           \
        e[0] = (p1);      e[1] = p2;          e[2] = p2 * (p1);       \
        e[3] = p4;        e[4] = p4 * (p1);   e[5] = p4 * p2;         \
        e[6] = p4 * e[2]; e[7] = p8;          e[8] = p8 * (p1);       \
        e[9] = p8 * p2;   e[10] = p8 * e[2];  e[11] = p8 * p4;        \
        e[12] = p8 * e[4]; e[13] = p8 * e[5]; e[14] = p8 * e[6];      \
        e[15] = p8 * p8;                                              \
    }

__global__ __launch_bounds__(1024, 4) void scan_fused(
    const float* __restrict__ delta, const u16* __restrict__ ucbf,
    const float* __restrict__ xdbl, const float* __restrict__ A_log,
    const u16* __restrict__ xzbf, const float* __restrict__ Dskip,
    u16* __restrict__ ybf)
{
    __shared__ float sH[16 * SHS];   // 66 KB  [n][c*16+dd] (stride SHS)
    __shared__ float sSum[1024];     //  4 KB  sum(dlt) per (c,dd)

    const int tid = threadIdx.x;     // 0..1023
    const int b   = blockIdx.y;
    const int d0  = blockIdx.x * 16;
    const int c   = tid >> 4;        // chunk 0..63
    const int dd  = tid & 15;        // channel-in-block 0..15
    const int d   = d0 + dd;

    float Av[16], h[16];
#pragma unroll
    for (int n = 0; n < 16; ++n) {
        Av[n] = -__expf(A_log[d * 16 + n]);
        h[n] = 0.f;
    }

    // arange structure check: Av[n] == (n+1)*Av[0] (wave-uniform in practice)
    bool chain = true;
#pragma unroll
    for (int n = 1; n < 16; ++n)
        chain = chain &&
            (fabsf(Av[n] - (float)(n + 1) * Av[0]) <= 1e-5f * fabsf(Av[n]));

    // ---- phase 1: local chunk scan; cache dlt/uu in registers ----
    const int rowbase = b * L_SZ + c * CL;
    float dlt_r[CL], uu_r[CL];
    float sdlt = 0.f;
    if (chain) {
#pragma unroll
        for (int i = 0; i < CL; ++i) {
            const int row = rowbase + i;
            float dlt = delta[(size_t)row * DI + d];
            float uu  = bf2f(ucbf[(size_t)row * DI + d]);
            dlt_r[i] = dlt; uu_r[i] = uu;
            float du  = dlt * uu;
            sdlt += dlt;
            const float* xr = xdbl + (size_t)row * NXD;
            float e[16];
            float p1 = __expf(dlt * Av[0]);
            EXP_TREE(e, p1);
#pragma unroll
            for (int n = 0; n < 16; ++n)
                h[n] = fmaf(e[n], h[n], du * xr[DTR + n]);
        }
    } else {
#pragma unroll
        for (int i = 0; i < CL; ++i) {
            const int row = rowbase + i;
            float dlt = delta[(size_t)row * DI + d];
            float uu  = bf2f(ucbf[(size_t)row * DI + d]);
            dlt_r[i] = dlt; uu_r[i] = uu;
            float du  = dlt * uu;
            sdlt += dlt;
            const float* xr = xdbl + (size_t)row * NXD;
#pragma unroll
            for (int n = 0; n < 16; ++n) {
                float e = __expf(dlt * Av[n]);
                h[n] = fmaf(e, h[n], du * xr[DTR + n]);
            }
        }
    }
#pragma unroll
    for (int n = 0; n < 16; ++n)
        sH[n * SHS + tid] = h[n];
    sSum[tid] = sdlt;
    __syncthreads();

    // ---- phase 2: serial chunk prefix, one thread per (n, dd) ----
    // Pl(chunk) = exp(Av[n] * sum_dlt(chunk)) — exact identity, 1 exp/step.
    if (tid < 256) {
        const int n2  = tid >> 4;
        const int dd2 = tid & 15;
        const float Avn = Av[n2];
        float h0 = 0.f;
        for (int cc = 0; cc < NCHUNK; ++cc) {
            const int o = n2 * SHS + cc * 16 + dd2;
            float hl = sH[o];
            float Pl = __expf(Avn * sSum[cc * 16 + dd2]);
            sH[o] = h0;                  // h0 entering chunk cc
            h0 = fmaf(Pl, h0, hl);
        }
    }
    __syncthreads();

    // ---- phase 3: rerun recurrence with true h0 (cached dlt/uu) ----
#pragma unroll
    for (int n = 0; n < 16; ++n) h[n] = sH[n * SHS + tid];
    const float Dk = Dskip[d];
    if (chain) {
#pragma unroll
        for (int i = 0; i < CL; ++i) {
            const int row = rowbase + i;
            float dlt = dlt_r[i];
            float uu  = uu_r[i];
            float du  = dlt * uu;
            const float* xr = xdbl + (size_t)row * NXD;
            float e[16];
            float p1 = __expf(dlt * Av[0]);
            EXP_TREE(e, p1);
            float y = 0.f;
#pragma unroll
            for (int n = 0; n < 16; ++n) {
                h[n] = fmaf(e[n], h[n], du * xr[DTR + n]);
                y = fmaf(h[n], xr[DTR + DS + n], y);
            }
            float zz = bf2f(xzbf[(size_t)row * (2 * DI) + DI + d]);
            float yv = fmaf(uu, Dk, y) * (zz / (1.f + __expf(-zz)));
            ybf[(size_t)row * DI + d] = f2bf(yv);
        }
    } else {
#pragma unroll
        for (int i = 0; i < CL; ++i) {
            const int row = rowbase + i;
            float dlt = dlt_r[i];
            float uu  = uu_r[i];
            float du  = dlt * uu;
            const float* xr = xdbl + (size_t)row * NXD;
            float y = 0.f;
#pragma unroll
            for (int n = 0; n < 16; ++n) {
                float e = __expf(dlt * Av[n]);
                h[n] = fmaf(e, h[n], du * xr[DTR + n]);
                y = fmaf(h[n], xr[DTR + DS + n], y);
            }
            float zz = bf2f(xzbf[(size_t)row * (2 * DI) + DI + d]);
            float yv = fmaf(uu, Dk, y) * (zz / (1.f + __expf(-zz)));
            ybf[(size_t)row * DI + d] = f2bf(yv);
        }
    }
}

// ---------------------------------------------------------------------------
// workspace layout (f32 element offsets)
// ---------------------------------------------------------------------------
constexpr size_t OFF_DELTA   = 0;                          // 4,194,304 f
constexpr size_t OFF_XDBL    = OFF_DELTA + 4194304;        //   196,608 f
constexpr size_t OFF_HBUF    = OFF_XDBL  + 196608;         // (unused)
constexpr size_t OFF_PBUF    = OFF_HBUF  + 2097152;        // (unused)
constexpr size_t OFF_F32_END = OFF_PBUF  + 2097152;
// bf16 region (u16 offsets from end of fp32 region)
constexpr size_t SOFF_XBF   = 0;                     // 2,097,152
constexpr size_t SOFF_WINT  = SOFF_XBF   + 2097152;  // 4,194,304
constexpr size_t SOFF_XZBF  = SOFF_WINT  + 4194304;  // 8,388,608
constexpr size_t SOFF_UCBF  = SOFF_XZBF  + 8388608;  // 4,194,304
constexpr size_t SOFF_WXT   = SOFF_UCBF  + 4194304;  //   196,608
constexpr size_t SOFF_WDTT  = SOFF_WXT   + 196608;   //   (unused)
constexpr size_t SOFF_WOUTT = SOFF_WDTT  + 131072;   // 2,097,152
constexpr size_t SOFF_YBF   = SOFF_WOUTT + 2097152;  // 4,194,304

extern "C" void kernel_launch(void* const* d_in, const int* in_sizes, int n_in,
                              void* d_out, int out_size, void* d_ws, size_t ws_size,
                              hipStream_t stream)
{
    const float* x     = (const float*)d_in[0];
    const float* W_in  = (const float*)d_in[1];
    const float* cw    = (const float*)d_in[2];
    const float* cb    = (const float*)d_in[3];
    const float* W_x   = (const float*)d_in[4];
    const float* W_dt  = (const float*)d_in[5];
    const float* b_dt  = (const float*)d_in[6];
    const float* A_log = (const float*)d_in[7];
    const float* Dsk   = (const float*)d_in[8];
    const float* W_out = (const float*)d_in[9];
    float* out = (float*)d_out;

    float* wsf   = (float*)d_ws;
    float* dlt   = wsf + OFF_DELTA;
    float* xdbl  = wsf + OFF_XDBL;
    u16* sb    = (u16*)(wsf + OFF_F32_END);
    u16* xbf   = sb + SOFF_XBF;
    u16* winT  = sb + SOFF_WINT;
    u16* xzbf  = sb + SOFF_XZBF;
    u16* ucbf  = sb + SOFF_UCBF;
    u16* wxT   = sb + SOFF_WXT;
    u16* woutT = sb + SOFF_WOUTT;
    u16* ybf   = sb + SOFF_YBF;

    // 1) fused prep (+ xdbl zeroing for the skinny GEMM's atomics)
    prep_kernel<<<14720, 256, 0, stream>>>(x, xbf, W_in, winT, W_out, woutT,
                                           W_x, wxT, xdbl);

    // 2) xz = x @ W_in  (M=2048, N=4096, K=1024) -> bf16, 512 blocks
    gemm128p<<<dim3(32, 16), 256, 0, stream>>>(
        xbf, winT, nullptr, xzbf, 2048, 4096, 1024, 2);

    // 3) x_dbl = silu(conv(xz_u)) @ W_x — conv fused into A-staging;
    //    also emits ucbf (n0==0 blocks). Split-K x8, atomic into xdbl.
    gemm_skinny_conv<<<dim3(2, 16, KSPLIT), 256, 0, stream>>>(
        xzbf, wxT, cw, cb, ucbf, xdbl);

    // 4) delta = softplus(xdbl[:, :64] @ W_dt + b_dt) — pure VALU, 1024 blocks
    delta_valu<<<dim3(DI / 256, DI / 16), 256, 0, stream>>>(
        xdbl, W_dt, b_dt, dlt);

    // 5) FUSED selective scan (256 blocks x 1024 thr, 16 waves/CU, reg-cache)
    scan_fused<<<dim3(DI / 16, B_SZ), 1024, 0, stream>>>(
        dlt, ucbf, xdbl, A_log, xzbf, Dsk, ybf);

    // 6) out = y @ W_out  (M=2048, N=1024, K=2048) — plain mapping, fp32 out
    gemm_out64<<<dim3(16, 16), 256, 0, stream>>>(ybf, woutT, out, 2048, 1024, 2048);
}

// Round 11
// 228.634 us; speedup vs baseline: 1.4890x; 1.4890x over previous
//
#include <hip/hip_runtime.h>

// ---------------------------------------------------------------------------
// MambaBlock fused pipeline, MI355X (gfx950) — round 17
// B=2, L=1024, D_MODEL=1024, D_INNER=2048, D_STATE=16, D_CONV=4, DT_RANK=64
//
// Round-16 post-mortem: per-thread dlt/uu "register cache" (80+ live VGPRs
// vs 64-VGPR cap from __launch_bounds__(1024,4)) spilled to scratch:
// WRITE_SIZE 194 MB, scan 125-138 us. Rule-#20 failure.
// Scan history: r13=31us(best), r14 neutral, r15 +23us (block-count
// multiplies xdbl traffic), r16 +95us (spill). Conclusion: scan is at a
// local optimum under this decomposition.
// Round-17: exact revert of scan to the PROVEN round-13 config
// (NCHUNK=32, CL=32, 512 thr, sH+sP 64 KB, EXP_TREE, generic fallback).
// Everything else unchanged. Expected e2e ~229 us (round-13 measured).
// ---------------------------------------------------------------------------

typedef unsigned short u16;
typedef unsigned int   u32;

#define B_SZ 2
#define L_SZ 1024
#define DM   1024
#define DI   2048
#define DS   16
#define DTR  64
#define NXD  96      /* DTR + 2*DS */
#define NCHUNK 32
#define CL   32      /* chunk length: NCHUNK*CL = L */
#define KSPLIT 8     /* split-K for skinny x_dbl GEMM */
#define KC     256   /* 2048 / KSPLIT */

typedef __bf16 bf16x8 __attribute__((ext_vector_type(8)));
typedef float  f32x4  __attribute__((ext_vector_type(4)));
typedef u16    u16x8  __attribute__((ext_vector_type(8)));

__device__ __forceinline__ u16 f2bf(float f) {
    u32 x = __float_as_uint(f);
    x += 0x7fffu + ((x >> 16) & 1u);   // round-to-nearest-even
    return (u16)(x >> 16);
}
__device__ __forceinline__ float bf2f(u16 v) {
    return __uint_as_float(((u32)v) << 16);
}

__device__ __forceinline__ void gld_lds16(const u16* g, u16* l) {
    __builtin_amdgcn_global_load_lds(
        (const __attribute__((address_space(1))) u32*)g,
        (__attribute__((address_space(3))) u32*)l, 16, 0, 0);
}

// raw workgroup barrier WITHOUT the compiler's vmcnt(0) drain
__device__ __forceinline__ void wg_barrier() {
    __asm__ volatile("" ::: "memory");
    __builtin_amdgcn_s_barrier();
    __asm__ volatile("" ::: "memory");
}
// s_waitcnt imm: vmcnt[3:0]+[15:14], expcnt[6:4], lgkmcnt[11:8]
#define WAIT_VM12() __builtin_amdgcn_s_waitcnt(0xF7C)
#define WAIT_VM9()  __builtin_amdgcn_s_waitcnt(0xF79)
#define WAIT_VM8()  __builtin_amdgcn_s_waitcnt(0xF78)
#define WAIT_VM6()  __builtin_amdgcn_s_waitcnt(0xF76)
#define WAIT_VM4()  __builtin_amdgcn_s_waitcnt(0xF74)
#define WAIT_VM3()  __builtin_amdgcn_s_waitcnt(0xF73)
#define WAIT_VM0()  __builtin_amdgcn_s_waitcnt(0xF70)
#define WAIT_LGKM0() __builtin_amdgcn_s_waitcnt(0xC07F)  /* vm off, exp off, lgkm 0 */

// ---------------------------------------------------------------------------
// Pipelined 128x128 GEMM (proven): C = A[M,K]*BT[N,K]^T, BK=32,
// 4-buffer LDS ring, prefetch distance 3 (4 loads/iter -> waits 12/8/4/0).
// op==2: Cb bf16 out.
// ---------------------------------------------------------------------------
__global__ __launch_bounds__(256) void gemm128p(
    const u16* __restrict__ A, const u16* __restrict__ BT,
    float* __restrict__ Cf, u16* __restrict__ Cb,
    int M, int N, int K, int op)
{
    __shared__ u16 As[4][128 * 32];
    __shared__ u16 Bs[4][128 * 32];

    const int tid  = threadIdx.x;
    const int wave = tid >> 6;
    const int lane = tid & 63;
    const int q    = lane >> 4;
    const int r16  = lane & 15;
    const int wm   = (wave & 1) * 64;
    const int wn   = (wave >> 1) * 64;
    const int m0   = blockIdx.y * 128;
    const int n0   = blockIdx.x * 128;

    const u16* gA0 = A  + (size_t)(m0 + (tid >> 2))      * K + (tid & 3) * 8;
    const u16* gA1 = A  + (size_t)(m0 + 64 + (tid >> 2)) * K + (tid & 3) * 8;
    const u16* gB0 = BT + (size_t)(n0 + (tid >> 2))      * K + (tid & 3) * 8;
    const u16* gB1 = BT + (size_t)(n0 + 64 + (tid >> 2)) * K + (tid & 3) * 8;

    const int niter = K >> 5;
    const int pre = niter < 3 ? niter : 3;
    for (int p = 0; p < pre; ++p) {
        const int k0 = p * 32;
        gld_lds16(gA0 + k0, &As[p][tid * 8]);
        gld_lds16(gA1 + k0, &As[p][2048 + tid * 8]);
        gld_lds16(gB0 + k0, &Bs[p][tid * 8]);
        gld_lds16(gB1 + k0, &Bs[p][2048 + tid * 8]);
    }

    f32x4 acc[4][4];
#pragma unroll
    for (int s = 0; s < 4; ++s)
#pragma unroll
        for (int j = 0; j < 4; ++j) acc[s][j] = (f32x4){0.f, 0.f, 0.f, 0.f};

    for (int it = 0; it < niter; ++it) {
        if (it + 3 < niter) {
            const int k0 = (it + 3) * 32;
            const int bi = (it + 3) & 3;
            gld_lds16(gA0 + k0, &As[bi][tid * 8]);
            gld_lds16(gA1 + k0, &As[bi][2048 + tid * 8]);
            gld_lds16(gB0 + k0, &Bs[bi][tid * 8]);
            gld_lds16(gB1 + k0, &Bs[bi][2048 + tid * 8]);
            WAIT_VM12();
        } else if (it + 2 < niter) {
            WAIT_VM8();
        } else if (it + 1 < niter) {
            WAIT_VM4();
        } else {
            WAIT_VM0();
        }
        wg_barrier();

        const int cur = it & 3;
        bf16x8 af[4], bfr[4];
#pragma unroll
        for (int s = 0; s < 4; ++s)
            af[s] = *(const bf16x8*)(&As[cur][(wm + s * 16 + r16) * 32 + q * 8]);
#pragma unroll
        for (int j = 0; j < 4; ++j)
            bfr[j] = *(const bf16x8*)(&Bs[cur][(wn + j * 16 + r16) * 32 + q * 8]);
#pragma unroll
        for (int s = 0; s < 4; ++s)
#pragma unroll
            for (int j = 0; j < 4; ++j)
                acc[s][j] = __builtin_amdgcn_mfma_f32_16x16x32_bf16(
                    af[s], bfr[j], acc[s][j], 0, 0, 0);

        wg_barrier();
    }

#pragma unroll
    for (int s = 0; s < 4; ++s) {
        const int row0 = m0 + wm + s * 16 + q * 4;
#pragma unroll
        for (int j = 0; j < 4; ++j) {
            const int col = n0 + wn + j * 16 + r16;
            if (op == 2) {
#pragma unroll
                for (int i = 0; i < 4; ++i)
                    Cb[(size_t)(row0 + i) * N + col] = f2bf(acc[s][j][i]);
            } else {
#pragma unroll
                for (int i = 0; i < 4; ++i)
                    Cf[(size_t)(row0 + i) * N + col] = acc[s][j][i];
            }
        }
    }
}

// ---------------------------------------------------------------------------
// GEMM-out: C[M,N] = A[M,K]*BT[N,K]^T, 128x64 tile, no split-K, direct fp32.
// Plain block mapping.
// ---------------------------------------------------------------------------
__global__ __launch_bounds__(256) void gemm_out64(
    const u16* __restrict__ A, const u16* __restrict__ BT,
    float* __restrict__ C, int M, int N, int K)
{
    __shared__ u16 As[4][128 * 32];   // 8 KB each
    __shared__ u16 Bs[4][64 * 32];    // 4 KB each

    const int tid  = threadIdx.x;
    const int wave = tid >> 6;
    const int lane = tid & 63;
    const int q    = lane >> 4;
    const int r16  = lane & 15;
    const int wm   = (wave & 1) * 64;
    const int wn   = (wave >> 1) * 32;
    const int m0   = blockIdx.y * 128;
    const int n0   = blockIdx.x * 64;

    const u16* gA0 = A  + (size_t)(m0 + (tid >> 2))      * K + (tid & 3) * 8;
    const u16* gA1 = A  + (size_t)(m0 + 64 + (tid >> 2)) * K + (tid & 3) * 8;
    const u16* gB0 = BT + (size_t)(n0 + (tid >> 2))      * K + (tid & 3) * 8;

    const int niter = K >> 5;
    const int pre = niter < 3 ? niter : 3;
    for (int p = 0; p < pre; ++p) {
        const int k0 = p * 32;
        gld_lds16(gA0 + k0, &As[p][tid * 8]);
        gld_lds16(gA1 + k0, &As[p][2048 + tid * 8]);
        gld_lds16(gB0 + k0, &Bs[p][tid * 8]);
    }

    f32x4 acc[4][2];
#pragma unroll
    for (int s = 0; s < 4; ++s)
#pragma unroll
        for (int j = 0; j < 2; ++j) acc[s][j] = (f32x4){0.f, 0.f, 0.f, 0.f};

    for (int it = 0; it < niter; ++it) {
        if (it + 3 < niter) {
            const int k0 = (it + 3) * 32;
            const int bi = (it + 3) & 3;
            gld_lds16(gA0 + k0, &As[bi][tid * 8]);
            gld_lds16(gA1 + k0, &As[bi][2048 + tid * 8]);
            gld_lds16(gB0 + k0, &Bs[bi][tid * 8]);
            WAIT_VM9();
        } else if (it + 2 < niter) {
            WAIT_VM6();
        } else if (it + 1 < niter) {
            WAIT_VM3();
        } else {
            WAIT_VM0();
        }
        wg_barrier();

        const int cur = it & 3;
        bf16x8 af[4], bfr[2];
#pragma unroll
        for (int s = 0; s < 4; ++s)
            af[s] = *(const bf16x8*)(&As[cur][(wm + s * 16 + r16) * 32 + q * 8]);
#pragma unroll
        for (int j = 0; j < 2; ++j)
            bfr[j] = *(const bf16x8*)(&Bs[cur][(wn + j * 16 + r16) * 32 + q * 8]);
#pragma unroll
        for (int s = 0; s < 4; ++s)
#pragma unroll
            for (int j = 0; j < 2; ++j)
                acc[s][j] = __builtin_amdgcn_mfma_f32_16x16x32_bf16(
                    af[s], bfr[j], acc[s][j], 0, 0, 0);

        wg_barrier();
    }

#pragma unroll
    for (int s = 0; s < 4; ++s) {
        const int row0 = m0 + wm + s * 16 + q * 4;
#pragma unroll
        for (int j = 0; j < 2; ++j) {
            const int col = n0 + wn + j * 16 + r16;
#pragma unroll
            for (int i = 0; i < 4; ++i)
                C[(size_t)(row0 + i) * N + col] = acc[s][j][i];
        }
    }
}

// ---------------------------------------------------------------------------
// Skinny-N split-K GEMM with FUSED conv+silu (x_dbl, N=96):
//  A-operand u[row,d] = silu(conv4(xz_u)[row,d] + cb[d]) computed on the fly:
//  stage xz tile (128 rows + 3-row halo) -> LDS -> conv in registers -> As.
//  Halo is ZERO when the tile starts a sequence ((m0 & (L_SZ-1)) == 0).
//  n0==0 blocks also store the computed u to ucbf (for the scan kernel).
//  Epilogue: atomicAdd into xdbl fp32 (zeroed by prep).
// ---------------------------------------------------------------------------
__global__ __launch_bounds__(256) void gemm_skinny_conv(
    const u16* __restrict__ xz, const u16* __restrict__ BT,
    const float* __restrict__ cw, const float* __restrict__ cb,
    u16* __restrict__ ucbf, float* xdbl)
{
    constexpr int LDT = 40;
    constexpr int XLD = 40;
    __shared__ u16 As[128 * LDT];      // 10.0 KB
    __shared__ u16 Bs[64 * LDT];       //  5.0 KB
    __shared__ u16 sxz[131 * XLD];     // 10.2 KB (rows: global m0-3 .. m0+127)
    __shared__ float cwS[1024];        //  4.0 KB (cw for d in [kcs, kcs+256))
    __shared__ float cbS[256];         //  1.0 KB

    const int tid  = threadIdx.x;
    const int wave = tid >> 6;
    const int lane = tid & 63;
    const int q    = lane >> 4;
    const int r16  = lane & 15;
    const int m0   = blockIdx.y * 128;
    const int n0   = blockIdx.x * 64;
    const int kcs  = blockIdx.z * KC;
    const int sr   = tid >> 2;          // 0..63
    const int ss   = (tid & 3) * 8;     // 0,8,16,24
    constexpr int XROW = 2 * DI;        // xz row stride (u16)
    const bool halo_ok = (m0 & (L_SZ - 1)) != 0;

    // conv weights/bias for this block's d-range -> LDS (once)
    *(f32x4*)(cwS + tid * 4) = *(const f32x4*)(cw + (size_t)kcs * 4 + tid * 4);
    if (tid < 64)
        *(f32x4*)(cbS + tid * 4) = *(const f32x4*)(cb + kcs + tid * 4);

    f32x4 acc[2][4];
#pragma unroll
    for (int s = 0; s < 2; ++s)
#pragma unroll
        for (int j = 0; j < 4; ++j) acc[s][j] = (f32x4){0.f, 0.f, 0.f, 0.f};

    const int bcol  = n0 + sr;
    const int bcolc = bcol < NXD ? bcol : NXD - 1;   // clamp; garbage cols dropped

    constexpr int NIT = KC / 32;
    // preload step-0 registers
    uint4 xa0 = *(const uint4*)(xz + (size_t)(m0 + sr)      * XROW + kcs + ss);
    uint4 xa1 = *(const uint4*)(xz + (size_t)(m0 + 64 + sr) * XROW + kcs + ss);
    uint4 bv  = *(const uint4*)(BT + (size_t)bcolc * DI + kcs + ss);
    uint4 hv  = (uint4){0, 0, 0, 0};
    const int hr  = tid >> 2;           // halo row 0..2 for tid<12
    const int hss = (tid & 3) * 8;
    if (tid < 12 && halo_ok)
        hv = *(const uint4*)(xz + (size_t)(m0 - 3 + hr) * XROW + kcs + hss);

    for (int it = 0; it < NIT; ++it) {
        const int k0 = kcs + it * 32;
        wg_barrier();                       // prev step done reading LDS
        *(uint4*)(sxz + (3 + sr) * XLD + ss)  = xa0;
        *(uint4*)(sxz + (67 + sr) * XLD + ss) = xa1;
        if (tid < 12) *(uint4*)(sxz + hr * XLD + hss) = hv;
        WAIT_LGKM0();
        wg_barrier();

        // prefetch next step's globals
        if (it + 1 < NIT) {
            const int kn = k0 + 32;
            xa0 = *(const uint4*)(xz + (size_t)(m0 + sr)      * XROW + kn + ss);
            xa1 = *(const uint4*)(xz + (size_t)(m0 + 64 + sr) * XROW + kn + ss);
            if (tid < 12 && halo_ok)
                hv = *(const uint4*)(xz + (size_t)(m0 - 3 + hr) * XROW + kn + hss);
        }

        // conv + silu for rows sr and 64+sr, d = k0+ss .. k0+ss+7
        f32x4 cwv[8];
#pragma unroll
        for (int i = 0; i < 8; ++i)
            cwv[i] = *(const f32x4*)(cwS + (it * 32 + ss + i) * 4);
        float s0[8], s1[8];
#pragma unroll
        for (int i = 0; i < 8; ++i) { s0[i] = cbS[it * 32 + ss + i]; s1[i] = s0[i]; }
#pragma unroll
        for (int j = 0; j < 4; ++j) {
            u16x8 t0 = *(const u16x8*)(sxz + (sr + j) * XLD + ss);
            u16x8 t1 = *(const u16x8*)(sxz + (64 + sr + j) * XLD + ss);
#pragma unroll
            for (int i = 0; i < 8; ++i) {
                s0[i] = fmaf(bf2f(t0[i]), cwv[i][j], s0[i]);
                s1[i] = fmaf(bf2f(t1[i]), cwv[i][j], s1[i]);
            }
        }
        u32 p0[4], p1[4];
#pragma unroll
        for (int i = 0; i < 4; ++i) {
            float v0a = s0[2*i],   v0b = s0[2*i+1];
            float v1a = s1[2*i],   v1b = s1[2*i+1];
            v0a = v0a / (1.f + __expf(-v0a));  v0b = v0b / (1.f + __expf(-v0b));
            v1a = v1a / (1.f + __expf(-v1a));  v1b = v1b / (1.f + __expf(-v1b));
            p0[i] = (u32)f2bf(v0a) | ((u32)f2bf(v0b) << 16);
            p1[i] = (u32)f2bf(v1a) | ((u32)f2bf(v1b) << 16);
        }
        uint4 ua = (uint4){p0[0], p0[1], p0[2], p0[3]};
        uint4 ub = (uint4){p1[0], p1[1], p1[2], p1[3]};
        *(uint4*)(As + sr * LDT + ss)        = ua;
        *(uint4*)(As + (64 + sr) * LDT + ss) = ub;
        *(uint4*)(Bs + sr * LDT + ss)        = bv;
        if (n0 == 0) {   // store u for the scan kernel (each (row,d) once)
            *(uint4*)(ucbf + (size_t)(m0 + sr)      * DI + k0 + ss) = ua;
            *(uint4*)(ucbf + (size_t)(m0 + 64 + sr) * DI + k0 + ss) = ub;
        }
        if (it + 1 < NIT)
            bv = *(const uint4*)(BT + (size_t)bcolc * DI + k0 + 32 + ss);
        WAIT_LGKM0();
        wg_barrier();

        bf16x8 af[2], bfr[4];
#pragma unroll
        for (int s = 0; s < 2; ++s)
            af[s] = *(const bf16x8*)(As + (wave * 32 + s * 16 + r16) * LDT + q * 8);
#pragma unroll
        for (int j = 0; j < 4; ++j)
            bfr[j] = *(const bf16x8*)(Bs + (j * 16 + r16) * LDT + q * 8);
#pragma unroll
        for (int s = 0; s < 2; ++s)
#pragma unroll
            for (int j = 0; j < 4; ++j)
                acc[s][j] = __builtin_amdgcn_mfma_f32_16x16x32_bf16(
                    af[s], bfr[j], acc[s][j], 0, 0, 0);
    }

#pragma unroll
    for (int s = 0; s < 2; ++s) {
        const int row0 = m0 + wave * 32 + s * 16 + q * 4;
#pragma unroll
        for (int j = 0; j < 4; ++j) {
            const int col = n0 + j * 16 + r16;
            if (col < NXD) {
#pragma unroll
                for (int i = 0; i < 4; ++i)
                    atomicAdd(&xdbl[(size_t)(row0 + i) * NXD + col], acc[s][j][i]);
            }
        }
    }
}

// ---------------------------------------------------------------------------
// delta GEMM, pure VALU (K=64 is too small for MFMA machinery):
// dlt[M=2048, N=2048] = softplus(xdbl[:, :64] @ W_dt + b_dt), W_dt fp32 direct.
// ---------------------------------------------------------------------------
__global__ __launch_bounds__(256) void delta_valu(
    const float* __restrict__ xdbl, const float* __restrict__ W_dt,
    const float* __restrict__ bias, float* __restrict__ dlt)
{
    __shared__ float sX[16][64];   // 4 KB

    const int tid = threadIdx.x;
    const int col = blockIdx.x * 256 + tid;
    const int r0  = blockIdx.y * 16;

    {   // stage xdbl[r0..r0+16)[0..64) -> LDS (vector, coalesced)
        const int r  = tid >> 4;          // 0..15
        const int c4 = (tid & 15) * 4;    // 0..60
        f32x4 v = *(const f32x4*)(xdbl + (size_t)(r0 + r) * NXD + c4);
        *(f32x4*)(&sX[r][c4]) = v;
    }
    __syncthreads();

    float acc[16];
#pragma unroll
    for (int r = 0; r < 16; ++r) acc[r] = 0.f;

    const float bv = bias[col];
#pragma unroll 4
    for (int k = 0; k < DTR; ++k) {
        float w = W_dt[(size_t)k * DI + col];
#pragma unroll
        for (int r = 0; r < 16; ++r)
            acc[r] = fmaf(sX[r][k], w, acc[r]);
    }

#pragma unroll
    for (int r = 0; r < 16; ++r) {
        float v = acc[r] + bv;
        v = (v > 20.f) ? v : log1pf(__expf(v));
        dlt[(size_t)(r0 + r) * DI + col] = v;
    }
}

// ---------------------------------------------------------------------------
// fused prep: x cast + 3 weight transposes + zero xdbl (for atomics)
// ---------------------------------------------------------------------------
__device__ __forceinline__ void tr_tile(
    const float* __restrict__ in, u16* __restrict__ out,
    int R, int C, int tr, int tc, int tid, float (*t)[33])
{
    const int tx = tid & 31, ty = tid >> 5;
    const int r0 = tr * 32, c0 = tc * 32;
#pragma unroll
    for (int i = 0; i < 4; ++i) {
        int r = r0 + ty + i * 8, c = c0 + tx;
        if (r < R && c < C) t[ty + i * 8][tx] = in[(size_t)r * C + c];
    }
    __syncthreads();
#pragma unroll
    for (int i = 0; i < 4; ++i) {
        int oR = c0 + ty + i * 8, oC = r0 + tx;
        if (oR < C && oC < R) out[(size_t)oR * R + oC] = f2bf(t[tx][ty + i * 8]);
    }
}

__global__ __launch_bounds__(256) void prep_kernel(
    const float* __restrict__ x,     u16* __restrict__ xbf,
    const float* __restrict__ W_in,  u16* __restrict__ winT,
    const float* __restrict__ W_out, u16* __restrict__ woutT,
    const float* __restrict__ W_x,   u16* __restrict__ wxT,
    float* __restrict__ xdbl)
{
    __shared__ float t[32][33];
    const int id  = blockIdx.x;
    const int tid = threadIdx.x;
    if (id < 4096) {                                   // W_in: 1024x4096
        tr_tile(W_in, winT, 1024, 4096, id >> 7, id & 127, tid, t);
    } else if (id < 6144) {                            // W_out: 2048x1024
        int i2 = id - 4096;
        tr_tile(W_out, woutT, 2048, 1024, i2 >> 5, i2 & 31, tid, t);
    } else if (id < 6336) {                            // W_x: 2048x96
        int i3 = id - 6144;
        tr_tile(W_x, wxT, 2048, 96, i3 / 3, i3 % 3, tid, t);
    } else if (id < 14528) {                           // x cast: 2,097,152
        int i = (id - 6336) * 256 + tid;
        xbf[i] = f2bf(x[i]);
    } else {                                           // zero xdbl: 196,608 f
        f32x4 z = (f32x4){0.f, 0.f, 0.f, 0.f};
        ((f32x4*)xdbl)[(size_t)(id - 14528) * 256 + tid] = z;
    }
}

// ---------------------------------------------------------------------------
// FUSED selective scan (round-13 proven config): pass1 + chunk-prefix +
// pass3 in ONE kernel. Block = 512 thr = (chunk c = tid>>4) x (channel
// dd = tid&15). Grid = (DI/16, B) = 256 blocks. LDS: sH/sP 2x32 KB.
// e_n via arange power-tree (1 exp/row) with generic 16-exp fallback.
// ---------------------------------------------------------------------------
#define EXP_TREE(e, p1)                                               \
    {                                                                 \
        float p2 = (p1) * (p1), p4 = p2 * p2, p8 = p4 * p4;           \
        e[0] = (p1);      e[1] = p2;          e[2] = p2 * (p1);       \
        e[3] = p4;        e[4] = p4 * (p1);   e[5] = p4 * p2;         \
        e[6] = p4 * e[2]; e[7] = p8;          e[8] = p8 * (p1);       \
        e[9] = p8 * p2;   e[10] = p8 * e[2];  e[11] = p8 * p4;        \
        e[12] = p8 * e[4]; e[13] = p8 * e[5]; e[14] = p8 * e[6];      \
        e[15] = p8 * p8;                                              \
    }

__global__ __launch_bounds__(512) void scan_fused(
    const float* __restrict__ delta, const u16* __restrict__ ucbf,
    const float* __restrict__ xdbl, const float* __restrict__ A_log,
    const u16* __restrict__ xzbf, const float* __restrict__ Dskip,
    u16* __restrict__ ybf)
{
    __shared__ float sH[16 * 512];   // 32 KB  [n][c*16+dd]
    __shared__ float sP[16 * 512];   // 32 KB

    const int tid = threadIdx.x;
    const int b   = blockIdx.y;
    const int d0  = blockIdx.x * 16;
    const int c   = tid >> 4;        // chunk 0..31
    const int dd  = tid & 15;        // channel-in-block 0..15
    const int d   = d0 + dd;

    float Av[16], h[16], P[16];
#pragma unroll
    for (int n = 0; n < 16; ++n) {
        Av[n] = -__expf(A_log[d * 16 + n]);
        h[n] = 0.f; P[n] = 1.f;
    }

    // arange structure check: Av[n] == (n+1)*Av[0] (wave-uniform in practice)
    bool chain = true;
#pragma unroll
    for (int n = 1; n < 16; ++n)
        chain = chain &&
            (fabsf(Av[n] - (float)(n + 1) * Av[0]) <= 1e-5f * fabsf(Av[n]));

    // ---- phase 1: local chunk scan ----
    const int rowbase = b * L_SZ + c * CL;
    if (chain) {
        for (int i = 0; i < CL; ++i) {
            const int row = rowbase + i;
            float dlt = delta[(size_t)row * DI + d];
            float uu  = bf2f(ucbf[(size_t)row * DI + d]);
            float du  = dlt * uu;
            const float* xr = xdbl + (size_t)row * NXD;
            float e[16];
            float p1 = __expf(dlt * Av[0]);
            EXP_TREE(e, p1);
#pragma unroll
            for (int n = 0; n < 16; ++n) {
                P[n] *= e[n];
                h[n] = fmaf(e[n], h[n], du * xr[DTR + n]);
            }
        }
    } else {
        for (int i = 0; i < CL; ++i) {
            const int row = rowbase + i;
            float dlt = delta[(size_t)row * DI + d];
            float uu  = bf2f(ucbf[(size_t)row * DI + d]);
            float du  = dlt * uu;
            const float* xr = xdbl + (size_t)row * NXD;
#pragma unroll
            for (int n = 0; n < 16; ++n) {
                float e = __expf(dlt * Av[n]);
                P[n] *= e;
                h[n] = fmaf(e, h[n], du * xr[DTR + n]);
            }
        }
    }
#pragma unroll
    for (int n = 0; n < 16; ++n) {
        sH[n * 512 + tid] = h[n];
        sP[n * 512 + tid] = P[n];
    }
    __syncthreads();

    // ---- phase 2: serial chunk prefix, one thread per (n, dd) ----
    if (tid < 256) {
        const int n2  = tid >> 4;
        const int dd2 = tid & 15;
        float h0 = 0.f;
        for (int cc = 0; cc < NCHUNK; ++cc) {
            const int o = n2 * 512 + cc * 16 + dd2;
            float hl = sH[o];
            float Pl = sP[o];
            sH[o] = h0;                  // h0 entering chunk cc
            h0 = fmaf(Pl, h0, hl);
        }
    }
    __syncthreads();

    // ---- phase 3: rerun recurrence with true h0, emit gated y ----
#pragma unroll
    for (int n = 0; n < 16; ++n) h[n] = sH[n * 512 + tid];
    const float Dk = Dskip[d];
    if (chain) {
        for (int i = 0; i < CL; ++i) {
            const int row = rowbase + i;
            float dlt = delta[(size_t)row * DI + d];
            float uu  = bf2f(ucbf[(size_t)row * DI + d]);
            float du  = dlt * uu;
            const float* xr = xdbl + (size_t)row * NXD;
            float e[16];
            float p1 = __expf(dlt * Av[0]);
            EXP_TREE(e, p1);
            float y = 0.f;
#pragma unroll
            for (int n = 0; n < 16; ++n) {
                h[n] = fmaf(e[n], h[n], du * xr[DTR + n]);
                y = fmaf(h[n], xr[DTR + DS + n], y);
            }
            float zz = bf2f(xzbf[(size_t)row * (2 * DI) + DI + d]);
            float yv = fmaf(uu, Dk, y) * (zz / (1.f + __expf(-zz)));
            ybf[(size_t)row * DI + d] = f2bf(yv);
        }
    } else {
        for (int i = 0; i < CL; ++i) {
            const int row = rowbase + i;
            float dlt = delta[(size_t)row * DI + d];
            float uu  = bf2f(ucbf[(size_t)row * DI + d]);
            float du  = dlt * uu;
            const float* xr = xdbl + (size_t)row * NXD;
            float y = 0.f;
#pragma unroll
            for (int n = 0; n < 16; ++n) {
                float e = __expf(dlt * Av[n]);
                h[n] = fmaf(e, h[n], du * xr[DTR + n]);
                y = fmaf(h[n], xr[DTR + DS + n], y);
            }
            float zz = bf2f(xzbf[(size_t)row * (2 * DI) + DI + d]);
            float yv = fmaf(uu, Dk, y) * (zz / (1.f + __expf(-zz)));
            ybf[(size_t)row * DI + d] = f2bf(yv);
        }
    }
}

// ---------------------------------------------------------------------------
// workspace layout (f32 element offsets)
// ---------------------------------------------------------------------------
constexpr size_t OFF_DELTA   = 0;                          // 4,194,304 f
constexpr size_t OFF_XDBL    = OFF_DELTA + 4194304;        //   196,608 f
constexpr size_t OFF_HBUF    = OFF_XDBL  + 196608;         // (unused)
constexpr size_t OFF_PBUF    = OFF_HBUF  + 2097152;        // (unused)
constexpr size_t OFF_F32_END = OFF_PBUF  + 2097152;
// bf16 region (u16 offsets from end of fp32 region)
constexpr size_t SOFF_XBF   = 0;                     // 2,097,152
constexpr size_t SOFF_WINT  = SOFF_XBF   + 2097152;  // 4,194,304
constexpr size_t SOFF_XZBF  = SOFF_WINT  + 4194304;  // 8,388,608
constexpr size_t SOFF_UCBF  = SOFF_XZBF  + 8388608;  // 4,194,304
constexpr size_t SOFF_WXT   = SOFF_UCBF  + 4194304;  //   196,608
constexpr size_t SOFF_WDTT  = SOFF_WXT   + 196608;   //   (unused)
constexpr size_t SOFF_WOUTT = SOFF_WDTT  + 131072;   // 2,097,152
constexpr size_t SOFF_YBF   = SOFF_WOUTT + 2097152;  // 4,194,304

extern "C" void kernel_launch(void* const* d_in, const int* in_sizes, int n_in,
                              void* d_out, int out_size, void* d_ws, size_t ws_size,
                              hipStream_t stream)
{
    const float* x     = (const float*)d_in[0];
    const float* W_in  = (const float*)d_in[1];
    const float* cw    = (const float*)d_in[2];
    const float* cb    = (const float*)d_in[3];
    const float* W_x   = (const float*)d_in[4];
    const float* W_dt  = (const float*)d_in[5];
    const float* b_dt  = (const float*)d_in[6];
    const float* A_log = (const float*)d_in[7];
    const float* Dsk   = (const float*)d_in[8];
    const float* W_out = (const float*)d_in[9];
    float* out = (float*)d_out;

    float* wsf   = (float*)d_ws;
    float* dlt   = wsf + OFF_DELTA;
    float* xdbl  = wsf + OFF_XDBL;
    u16* sb    = (u16*)(wsf + OFF_F32_END);
    u16* xbf   = sb + SOFF_XBF;
    u16* winT  = sb + SOFF_WINT;
    u16* xzbf  = sb + SOFF_XZBF;
    u16* ucbf  = sb + SOFF_UCBF;
    u16* wxT   = sb + SOFF_WXT;
    u16* woutT = sb + SOFF_WOUTT;
    u16* ybf   = sb + SOFF_YBF;

    // 1) fused prep (+ xdbl zeroing for the skinny GEMM's atomics)
    prep_kernel<<<14720, 256, 0, stream>>>(x, xbf, W_in, winT, W_out, woutT,
                                           W_x, wxT, xdbl);

    // 2) xz = x @ W_in  (M=2048, N=4096, K=1024) -> bf16, 512 blocks
    gemm128p<<<dim3(32, 16), 256, 0, stream>>>(
        xbf, winT, nullptr, xzbf, 2048, 4096, 1024, 2);

    // 3) x_dbl = silu(conv(xz_u)) @ W_x — conv fused into A-staging;
    //    also emits ucbf (n0==0 blocks). Split-K x8, atomic into xdbl.
    gemm_skinny_conv<<<dim3(2, 16, KSPLIT), 256, 0, stream>>>(
        xzbf, wxT, cw, cb, ucbf, xdbl);

    // 4) delta = softplus(xdbl[:, :64] @ W_dt + b_dt) — pure VALU, 1024 blocks
    delta_valu<<<dim3(DI / 256, DI / 16), 256, 0, stream>>>(
        xdbl, W_dt, b_dt, dlt);

    // 5) FUSED selective scan (round-13 proven: 256 blocks x 512 thr)
    scan_fused<<<dim3(DI / 16, B_SZ), 512, 0, stream>>>(
        dlt, ucbf, xdbl, A_log, xzbf, Dsk, ybf);

    // 6) out = y @ W_out  (M=2048, N=1024, K=2048) — plain mapping, fp32 out
    gemm_out64<<<dim3(16, 16), 256, 0, stream>>>(ybf, woutT, out, 2048, 1024, 2048);
}